// Round 7
// baseline (284.876 us; speedup 1.0000x reference)
//
#include <hip/hip_runtime.h>
#include <math.h>

#define EPS_ 1e-8f
#define LAM_ 1e-3f

// 16-lane row sum via DPP (VALU, no DS pipe): quad_perm xor1, xor2, row_ror:4, row_ror:8.
// Lane groups must align with DPP rows (lanes [16k,16k+16)) — our cc dimension does.
__device__ __forceinline__ float dpp_sum16(float x) {
    int v;
    v = __builtin_amdgcn_update_dpp(0, __float_as_int(x), 0xB1, 0xf, 0xf, true);   // quad_perm [1,0,3,2] = xor1
    x += __int_as_float(v);
    v = __builtin_amdgcn_update_dpp(0, __float_as_int(x), 0x4E, 0xf, 0xf, true);   // quad_perm [2,3,0,1] = xor2
    x += __int_as_float(v);
    v = __builtin_amdgcn_update_dpp(0, __float_as_int(x), 0x124, 0xf, 0xf, true);  // row_ror:4
    x += __int_as_float(v);
    v = __builtin_amdgcn_update_dpp(0, __float_as_int(x), 0x128, 0xf, 0xf, true);  // row_ror:8
    x += __int_as_float(v);
    return x;  // every lane in the 16-lane row holds the row sum
}

// ---------------- K1: 5x5 conv s2 p2 + BN + ReLU ----------------
__global__ __launch_bounds__(256) void k_conv_bn(
    const float* __restrict__ x, const float* __restrict__ cw, const float* __restrict__ cb,
    const float* __restrict__ g, const float* __restrict__ bb,
    const float* __restrict__ mean, const float* __restrict__ var,
    float* __restrict__ y)
{
    int t = blockIdx.x * 256 + threadIdx.x;          // < 64*16*16*64
    int ch = t & 63, w = (t >> 6) & 15, h = (t >> 10) & 15, b = t >> 14;
    const float* xb = x + b * 1024;
    const float* wc = cw + ch * 25;
    float acc = cb[ch];
    #pragma unroll
    for (int kh = 0; kh < 5; ++kh) {
        int ih = h * 2 - 2 + kh;
        if (ih < 0 || ih > 31) continue;
        #pragma unroll
        for (int kw = 0; kw < 5; ++kw) {
            int iw = w * 2 - 2 + kw;
            if (iw < 0 || iw > 31) continue;
            acc = fmaf(xb[ih * 32 + iw], wc[kh * 5 + kw], acc);
        }
    }
    float v = (acc - mean[ch]) * (g[ch] * rsqrtf(var[ch] + 1e-3f)) + bb[ch];
    y[t] = fmaxf(v, 0.f);
}

// ---------------- K-prep: all weight transposes ----------------
__global__ __launch_bounds__(256) void k_transw(
    const float* __restrict__ w1, const float* __restrict__ w2, const float* __restrict__ wc,
    const float* __restrict__ pw, const float* __restrict__ pb,
    const float* __restrict__ aw, const float* __restrict__ ab,
    float* __restrict__ w1t, float* __restrict__ w2t, float* __restrict__ wct,
    float* __restrict__ wpt)
{
    int t = blockIdx.x * 256 + threadIdx.x;
    if (t < 3616 * 16) {
        int m = t >> 4, e = t & 15, r = e >> 2, q = e & 3;
        const float* src; float* dst;
        if (m < 1152)      { src = w1 + m * 16;          dst = w1t + m * 16; }
        else if (m < 3456) { src = w2 + (m - 1152) * 16; dst = w2t + (m - 1152) * 16; }
        else               { src = wc + (m - 3456) * 16; dst = wct + (m - 3456) * 16; }
        dst[e] = src[q * 4 + r];
    } else if (t < 3616 * 16 + 65 * 136) {
        int idx = t - 3616 * 16;
        int o = idx % 136, j = idx / 136;
        float v;
        if (j == 64)       v = (o < 128) ? pb[o] : ab[o - 128];
        else if (o < 128)  v = pw[o * 64 + j];
        else               v = aw[(o - 128) * 64 + j];
        wpt[j * 136 + o] = v;
    }
}

// ---------------- K2: primary caps (coalesced GEMM) ----------------
__global__ __launch_bounds__(256) void k_prim(
    const float* __restrict__ y, const float* __restrict__ wpt,
    float* __restrict__ poseP, float* __restrict__ aP)
{
    int t = blockIdx.x * 256 + threadIdx.x;
    if (t >= 16384 * 34) return;
    int oq = t % 34;
    int pos = t / 34;
    const float* yp = y + pos * 64;
    float4 acc = *(const float4*)(wpt + 64 * 136 + oq * 4);   // bias row
    #pragma unroll
    for (int j0 = 0; j0 < 64; j0 += 4) {
        float4 y4 = *(const float4*)(yp + j0);
        float4 w0 = *(const float4*)(wpt + (j0 + 0) * 136 + oq * 4);
        float4 w1 = *(const float4*)(wpt + (j0 + 1) * 136 + oq * 4);
        float4 w2 = *(const float4*)(wpt + (j0 + 2) * 136 + oq * 4);
        float4 w3 = *(const float4*)(wpt + (j0 + 3) * 136 + oq * 4);
        acc.x = fmaf(y4.x, w0.x, fmaf(y4.y, w1.x, fmaf(y4.z, w2.x, fmaf(y4.w, w3.x, acc.x))));
        acc.y = fmaf(y4.x, w0.y, fmaf(y4.y, w1.y, fmaf(y4.z, w2.y, fmaf(y4.w, w3.y, acc.y))));
        acc.z = fmaf(y4.x, w0.z, fmaf(y4.y, w1.z, fmaf(y4.z, w2.z, fmaf(y4.w, w3.z, acc.z))));
        acc.w = fmaf(y4.x, w0.w, fmaf(y4.y, w1.w, fmaf(y4.z, w2.w, fmaf(y4.w, w3.w, acc.w))));
    }
    if (oq < 32) {
        ((float4*)(poseP + pos * 128))[oq] = acc;
    } else {
        int oo = (oq - 32) * 4;
        float* ad = aP + pos * 8 + oo;
        ad[0] = 1.f / (1.f + __expf(-acc.x));
        ad[1] = 1.f / (1.f + __expf(-acc.y));
        ad[2] = 1.f / (1.f + __expf(-acc.z));
        ad[3] = 1.f / (1.f + __expf(-acc.w));
    }
}

// ---------------- split-wave capsule routing (stages 1 & 2) ----------------
template<int N, int C, int K, int S, int H, int W, int Bi, int OH, int OW, int NW>
__global__ __launch_bounds__(NW * 64) void k_caps_split(
    const float* __restrict__ pose_in,  // (b,H,W,Bi,16)
    const float* __restrict__ a_in,     // (b,H,W,Bi)
    const float* __restrict__ Wt,       // (N,C,16) r-major transposed
    const float* __restrict__ bu, const float* __restrict__ ba,
    float* __restrict__ pose_out,       // (b,OH,OW,C,16)
    float* __restrict__ a_out)          // (b,OH,OW,C)
{
    static_assert(C == 16 && N % (NW * 4) == 0, "");
    constexpr int BLK = NW * 64;
    constexpr int IW  = N / NW;     // i's per wave
    constexpr int NIT = IW / 4;     // i's per thread

    __shared__ __align__(16) float pp[N * 16];
    __shared__ float ap[N];
    __shared__ __align__(16) float red1[NW][16][20];
    __shared__ __align__(16) float red2[NW][16][20];
    __shared__ float redr[NW][16];

    const int t = threadIdx.x;
    const int w = t >> 6, lane = t & 63;
    const int n_ = blockIdx.x;
    const int b = n_ / (OH * OW);
    const int rem = n_ % (OH * OW);
    const int oh = rem / OW, ow = rem % OW;

    // ---- gather patch pose (float4) and activation into LDS (block-wide) ----
    for (int idx = t; idx < N * 4; idx += BLK) {
        int i = idx >> 2, f = idx & 3;
        int bi = i % Bi;
        int k2 = i / Bi;
        int sw = ow * S + (k2 % K), sh = oh * S + (k2 / K);
        const float4* src = (const float4*)(pose_in + (((b * H + sh) * W + sw) * Bi + bi) * 16);
        ((float4*)(pp + i * 16))[f] = src[f];
    }
    for (int i = t; i < N; i += BLK) {
        int bi = i % Bi;
        int k2 = i / Bi;
        int sw = ow * S + (k2 % K), sh = oh * S + (k2 / K);
        ap[i] = a_in[((b * H + sh) * W + sw) * Bi + bi];
    }
    __syncthreads();

    // ---- inv0 = 1/(sum a + C^2*EPS) ----
    float suma = 0.f;
    for (int i = lane; i < N; i += 64) suma += ap[i];
    suma = dpp_sum16(suma);
    suma += __shfl_xor(suma, 16, 64);
    suma += __shfl_xor(suma, 32, 64);
    const float inv0 = __builtin_amdgcn_rcpf(suma + (float)(C * C) * EPS_);

    const int ig = (lane >> 4) & 3, cc = lane & 15;
    const int ibase = w * IW;

    // ================= pass A: mu0 =================
    float muU[16];
    #pragma unroll
    for (int e2 = 0; e2 < 16; ++e2) muU[e2] = 0.f;
    #pragma unroll 2
    for (int ii = 0; ii < NIT; ++ii) {
        int i = ibase + ig + ii * 4;
        const float4* pi4 = (const float4*)(pp + i * 16);
        const float4* wt4 = (const float4*)(Wt + (i * C + cc) * 16);
        float4 pv[4] = { pi4[0], pi4[1], pi4[2], pi4[3] };
        float4 wv[4] = { wt4[0], wt4[1], wt4[2], wt4[3] };
        float co = ap[i] * inv0;
        #pragma unroll
        for (int e2 = 0; e2 < 16; ++e2) {
            float4 p4 = pv[e2 >> 2], w4 = wv[e2 & 3];
            float v = p4.x * w4.x + p4.y * w4.y + p4.z * w4.z + p4.w * w4.w;
            muU[e2] = fmaf(co, v, muU[e2]);
        }
    }
    #pragma unroll
    for (int e2 = 0; e2 < 16; ++e2) {
        muU[e2] += __shfl_xor(muU[e2], 16, 64);
        muU[e2] += __shfl_xor(muU[e2], 32, 64);   // wave-partial mu0[cc][e2]
    }
    if (lane < 16) {
        float4* dst = (float4*)&red1[w][lane][0];
        dst[0] = *(float4*)&muU[0];
        dst[1] = *(float4*)&muU[4];
        dst[2] = *(float4*)&muU[8];
        dst[3] = *(float4*)&muU[12];
    }
    __syncthreads();

    float m0[16];
    {
        #pragma unroll
        for (int f = 0; f < 4; ++f) {
            float4 s = *(const float4*)&red1[0][cc][f * 4];
            #pragma unroll
            for (int ww = 1; ww < NW; ++ww) {
                float4 p = *(const float4*)&red1[ww][cc][f * 4];
                s.x += p.x; s.y += p.y; s.z += p.z; s.w += p.w;
            }
            *(float4*)&m0[f * 4] = s;
        }
    }
    __syncthreads();   // red1 reused below

    // ================= pass B: dist -> rm fused with Sv/Sv2/rsum =================
    float SvU[16], Sv2U[16];
    #pragma unroll
    for (int e2 = 0; e2 < 16; ++e2) { SvU[e2] = 0.f; Sv2U[e2] = 0.f; }
    float rsum = 0.f;
    #pragma unroll 2
    for (int ii = 0; ii < NIT; ++ii) {
        int i = ibase + ig + ii * 4;
        const float4* pi4 = (const float4*)(pp + i * 16);
        const float4* wt4 = (const float4*)(Wt + (i * C + cc) * 16);
        float4 pv[4] = { pi4[0], pi4[1], pi4[2], pi4[3] };
        float4 wv[4] = { wt4[0], wt4[1], wt4[2], wt4[3] };
        float vv[16];
        float dist = EPS_;
        #pragma unroll
        for (int e2 = 0; e2 < 16; ++e2) {
            float4 p4 = pv[e2 >> 2], w4 = wv[e2 & 3];
            float v = p4.x * w4.x + p4.y * w4.y + p4.z * w4.z + p4.w * w4.w;
            vv[e2] = v;
            float d = v - m0[e2];
            dist = fmaf(d, d, dist);
        }
        float inv = __builtin_amdgcn_rcpf(dist);
        float s = dpp_sum16(inv);                     // sum over cc (VALU DPP, no DS)
        float r1 = inv * __builtin_amdgcn_rcpf(s + EPS_);
        float rm = r1 * r1 * ap[i];
        rsum += rm;
        #pragma unroll
        for (int e2 = 0; e2 < 16; ++e2) {
            float rv = rm * vv[e2];
            SvU[e2] += rv;
            Sv2U[e2] = fmaf(rv, vv[e2], Sv2U[e2]);
        }
    }
    #pragma unroll
    for (int e2 = 0; e2 < 16; ++e2) {
        SvU[e2] += __shfl_xor(SvU[e2], 16, 64);
        SvU[e2] += __shfl_xor(SvU[e2], 32, 64);
        Sv2U[e2] += __shfl_xor(Sv2U[e2], 16, 64);
        Sv2U[e2] += __shfl_xor(Sv2U[e2], 32, 64);
    }
    rsum += __shfl_xor(rsum, 16, 64);
    rsum += __shfl_xor(rsum, 32, 64);
    if (lane < 16) {
        float4* d1 = (float4*)&red1[w][lane][0];
        float4* d2 = (float4*)&red2[w][lane][0];
        d1[0] = *(float4*)&SvU[0];  d1[1] = *(float4*)&SvU[4];
        d1[2] = *(float4*)&SvU[8];  d1[3] = *(float4*)&SvU[12];
        d2[0] = *(float4*)&Sv2U[0]; d2[1] = *(float4*)&Sv2U[4];
        d2[2] = *(float4*)&Sv2U[8]; d2[3] = *(float4*)&Sv2U[12];
        redr[w][lane] = rsum;
    }
    __syncthreads();

    // ================= epilogue: wave 0 only =================
    if (w == 0) {
        float SvT[16], Sv2T[16];
        #pragma unroll
        for (int f = 0; f < 4; ++f) {
            float4 s1 = *(const float4*)&red1[0][cc][f * 4];
            float4 s2 = *(const float4*)&red2[0][cc][f * 4];
            #pragma unroll
            for (int ww = 1; ww < NW; ++ww) {
                float4 p1 = *(const float4*)&red1[ww][cc][f * 4];
                float4 p2 = *(const float4*)&red2[ww][cc][f * 4];
                s1.x += p1.x; s1.y += p1.y; s1.z += p1.z; s1.w += p1.w;
                s2.x += p2.x; s2.y += p2.y; s2.z += p2.z; s2.w += p2.w;
            }
            *(float4*)&SvT[f * 4] = s1;
            *(float4*)&Sv2T[f * 4] = s2;
        }
        float R = 0.f;
        #pragma unroll
        for (int ww = 0; ww < NW; ++ww) R += redr[ww][cc];

        const float id = 1.f / (R + EPS_);
        const float S0 = R * id;
        const float buc_ = bu[cc];
        float cs = 0.f;
        float4 outv[4];
        #pragma unroll
        for (int e2 = 0; e2 < 16; ++e2) {
            float Sv = SvT[e2] * id;
            float Sv2 = Sv2T[e2] * id;
            float sigma = fmaxf(Sv2 + Sv * Sv * (S0 - 2.f), 0.f) + EPS_;
            cs += (buc_ + 0.5f * __logf(sigma)) * R;
            ((float*)outv)[e2] = Sv;
        }
        if (lane < 16) {
            float4* pd = (float4*)(pose_out + (n_ * C + cc) * 16);
            pd[0] = outv[0]; pd[1] = outv[1]; pd[2] = outv[2]; pd[3] = outv[3];
            a_out[n_ * C + cc] = 1.f / (1.f + __expf(-(LAM_ * (ba[cc] - cs))));
        }
    }
}

// ---------------- block-wide caps (class layer, COORDS) ----------------
template<int N, int C, int H, int W, int Bi, int BLK>
__global__ __launch_bounds__(BLK) void k_caps_class(
    const float* __restrict__ pose_in, const float* __restrict__ a_in,
    const float* __restrict__ Wt,
    const float* __restrict__ bu, const float* __restrict__ ba,
    float* __restrict__ a_out)
{
    constexpr int NW  = BLK / 64;
    constexpr int NIG = BLK / 16;
    constexpr int NIT = (N + NIG - 1) / NIG;

    __shared__ __align__(16) float pp[N * 16];
    __shared__ float ap[N];
    __shared__ float coeff0[N];
    __shared__ float mu0[16 * 17];
    __shared__ float red1[NW * C * 17];
    __shared__ float red2[NW * C * 17];
    __shared__ float redr[NW * C];

    const int t = threadIdx.x;
    const int lane = t & 63;
    const int w = t >> 6;
    const int b = blockIdx.x;

    for (int idx = t; idx < N * 4; idx += BLK) {
        int i = idx >> 2, f = idx & 3;
        int bi = i % Bi;
        int hw = i / Bi;
        int sw = hw % W, sh = hw / W;
        const float4* src = (const float4*)(pose_in + (((b * H + sh) * W + sw) * Bi + bi) * 16);
        ((float4*)(pp + i * 16))[f] = src[f];
    }
    for (int i = t; i < N; i += BLK) {
        int bi = i % Bi;
        int hw = i / Bi;
        int sw = hw % W, sh = hw / W;
        ap[i] = a_in[((b * H + sh) * W + sw) * Bi + bi];
    }
    __syncthreads();

    {
        float part = 0.f;
        for (int i = t; i < N; i += BLK) part += ap[i];
        part = dpp_sum16(part);
        part += __shfl_xor(part, 16, 64);
        part += __shfl_xor(part, 32, 64);
        if (lane == 0) red1[w] = part;
        __syncthreads();
        float s = 0.f;
        #pragma unroll
        for (int ww = 0; ww < NW; ++ww) s += red1[ww];
        float inv0 = __builtin_amdgcn_rcpf(s + (float)(C * C) * EPS_);
        for (int i = t; i < N; i += BLK) coeff0[i] = ap[i] * inv0;
        __syncthreads();
    }

    const int ig = t >> 4, cc = t & 15;

    // pass A
    {
        float muU[16];
        #pragma unroll
        for (int e2 = 0; e2 < 16; ++e2) muU[e2] = 0.f;
        if (cc < C) {
            for (int ii = 0; ii < NIT; ++ii) {
                int i = ig + ii * NIG;
                if (i < N) {
                    const float4* pi4 = (const float4*)(pp + i * 16);
                    const float4* wt4 = (const float4*)(Wt + ((i % Bi) * C + cc) * 16);
                    float4 pv[4] = { pi4[0], pi4[1], pi4[2], pi4[3] };
                    float4 wv[4] = { wt4[0], wt4[1], wt4[2], wt4[3] };
                    float co = coeff0[i];
                    float chv = (float)(i / (W * Bi)) * (1.f / H);
                    float cwv = (float)((i / Bi) % W) * (1.f / W);
                    #pragma unroll
                    for (int e2 = 0; e2 < 16; ++e2) {
                        float4 p4 = pv[e2 >> 2], w4 = wv[e2 & 3];
                        float v = p4.x * w4.x + p4.y * w4.y + p4.z * w4.z + p4.w * w4.w;
                        if (e2 == 0) v += chv;
                        if (e2 == 1) v += cwv;
                        muU[e2] = fmaf(co, v, muU[e2]);
                    }
                }
            }
        }
        #pragma unroll
        for (int e2 = 0; e2 < 16; ++e2) {
            float xv = muU[e2];
            xv += __shfl_xor(xv, 16, 64);
            xv += __shfl_xor(xv, 32, 64);
            if (lane < 16 && lane < C) red1[(w * C + lane) * 17 + e2] = xv;
        }
        __syncthreads();
        if (t < 256) {
            int c = t >> 4, e = t & 15;
            if (c < C) {
                float m = 0.f;
                #pragma unroll
                for (int ww = 0; ww < NW; ++ww) m += red1[(ww * C + c) * 17 + e];
                mu0[c * 17 + e] = m;
            }
        }
        __syncthreads();
    }

    // pass B
    {
        float m0[16];
        if (cc < C) {
            #pragma unroll
            for (int e2 = 0; e2 < 16; ++e2) m0[e2] = mu0[cc * 17 + e2];
        }
        float SvU[16], Sv2U[16];
        #pragma unroll
        for (int e2 = 0; e2 < 16; ++e2) { SvU[e2] = 0.f; Sv2U[e2] = 0.f; }
        float rsumP = 0.f;

        for (int ii = 0; ii < NIT; ++ii) {
            int i = ig + ii * NIG;
            bool act = (i < N);
            float inv = 0.f;
            float vv[16];
            if (act && cc < C) {
                const float4* pi4 = (const float4*)(pp + i * 16);
                const float4* wt4 = (const float4*)(Wt + ((i % Bi) * C + cc) * 16);
                float4 pv[4] = { pi4[0], pi4[1], pi4[2], pi4[3] };
                float4 wv[4] = { wt4[0], wt4[1], wt4[2], wt4[3] };
                float chv = (float)(i / (W * Bi)) * (1.f / H);
                float cwv = (float)((i / Bi) % W) * (1.f / W);
                float dist = EPS_;
                #pragma unroll
                for (int e2 = 0; e2 < 16; ++e2) {
                    float4 p4 = pv[e2 >> 2], w4 = wv[e2 & 3];
                    float v = p4.x * w4.x + p4.y * w4.y + p4.z * w4.z + p4.w * w4.w;
                    if (e2 == 0) v += chv;
                    if (e2 == 1) v += cwv;
                    vv[e2] = v;
                    float d = v - m0[e2];
                    dist = fmaf(d, d, dist);
                }
                inv = __builtin_amdgcn_rcpf(dist);
            }
            float s = dpp_sum16(inv);               // sum over cc lanes (cc>=C contribute 0)
            if (act && cc < C) {
                float r1 = inv * __builtin_amdgcn_rcpf(s + EPS_);
                float rm = r1 * r1 * ap[i];
                rsumP += rm;
                #pragma unroll
                for (int e2 = 0; e2 < 16; ++e2) {
                    SvU[e2] = fmaf(rm, vv[e2], SvU[e2]);
                    Sv2U[e2] = fmaf(rm * vv[e2], vv[e2], Sv2U[e2]);
                }
            }
        }
        #pragma unroll
        for (int e2 = 0; e2 < 16; ++e2) {
            float xv = SvU[e2];
            xv += __shfl_xor(xv, 16, 64);
            xv += __shfl_xor(xv, 32, 64);
            float yv = Sv2U[e2];
            yv += __shfl_xor(yv, 16, 64);
            yv += __shfl_xor(yv, 32, 64);
            if (lane < 16 && lane < C) {
                red1[(w * C + lane) * 17 + e2] = xv;
                red2[(w * C + lane) * 17 + e2] = yv;
            }
        }
        {
            float rv = rsumP;
            rv += __shfl_xor(rv, 16, 64);
            rv += __shfl_xor(rv, 32, 64);
            if (lane < 16 && lane < C) redr[w * C + lane] = rv;
        }
        __syncthreads();
    }

    if (t < 256) {
        int c = t >> 4, e = t & 15;
        if (c < C) {
            float SvT = 0.f, Sv2T = 0.f, R = 0.f;
            #pragma unroll
            for (int ww = 0; ww < NW; ++ww) {
                SvT  += red1[(ww * C + c) * 17 + e];
                Sv2T += red2[(ww * C + c) * 17 + e];
                R    += redr[ww * C + c];
            }
            float id = 1.f / (R + EPS_);
            float S0 = R * id;
            float Sv = SvT * id;
            float Sv2 = Sv2T * id;
            float sigma = fmaxf(Sv2 + Sv * Sv * (S0 - 2.f), 0.f) + EPS_;
            float cost = (bu[c] + 0.5f * __logf(sigma)) * R;
            float cs = dpp_sum16(cost);             // sum over e (lane bits 0-3)
            if (e == 0) a_out[b * C + c] = 1.f / (1.f + __expf(-(LAM_ * (ba[c] - cs))));
        }
    }
}

extern "C" void kernel_launch(void* const* d_in, const int* in_sizes, int n_in,
                              void* d_out, int out_size, void* d_ws, size_t ws_size,
                              hipStream_t stream)
{
    const float* x   = (const float*)d_in[0];
    const float* c1w = (const float*)d_in[1];
    const float* c1b = (const float*)d_in[2];
    const float* bng = (const float*)d_in[3];
    const float* bnb = (const float*)d_in[4];
    const float* bnm = (const float*)d_in[5];
    const float* bnv = (const float*)d_in[6];
    const float* ppw = (const float*)d_in[7];
    const float* ppb = (const float*)d_in[8];
    const float* paw = (const float*)d_in[9];
    const float* pab = (const float*)d_in[10];
    const float* w1  = (const float*)d_in[11];
    const float* bu1 = (const float*)d_in[12];
    const float* ba1 = (const float*)d_in[13];
    const float* w2  = (const float*)d_in[14];
    const float* bu2 = (const float*)d_in[15];
    const float* ba2 = (const float*)d_in[16];
    const float* wcp = (const float*)d_in[17];
    const float* buc = (const float*)d_in[18];
    const float* bac = (const float*)d_in[19];
    float* out = (float*)d_out;

    float* ws    = (float*)d_ws;
    float* y     = ws;               // 64*16*16*64      = 1048576
    float* poseP = y + 1048576;      // 64*16*16*128     = 2097152
    float* aP    = poseP + 2097152;  // 64*16*16*8       = 131072
    float* pose1 = aP + 131072;      // 64*7*7*16*16     = 802816
    float* a1    = pose1 + 802816;   // 64*7*7*16        = 50176
    float* pose2 = a1 + 50176;       // 64*5*5*16*16     = 409600
    float* a2    = pose2 + 409600;   // 64*5*5*16        = 25600
    float* w1t   = a2 + 25600;       // 18432
    float* w2t   = w1t + 18432;      // 36864
    float* wct   = w2t + 36864;      // 2560
    float* wpt   = wct + 2560;       // 65*136 = 8840

    hipLaunchKernelGGL(k_transw, dim3((3616 * 16 + 65 * 136 + 255) / 256), dim3(256), 0, stream,
                       w1, w2, wcp, ppw, ppb, paw, pab, w1t, w2t, wct, wpt);
    hipLaunchKernelGGL(k_conv_bn, dim3(4096), dim3(256), 0, stream,
                       x, c1w, c1b, bng, bnb, bnm, bnv, y);
    hipLaunchKernelGGL(k_prim, dim3((16384 * 34 + 255) / 256), dim3(256), 0, stream,
                       y, wpt, poseP, aP);
    // stage 1: N=72, C=16, 3136 positions, NW=2 (128 thr/block)
    hipLaunchKernelGGL((k_caps_split<72, 16, 3, 2, 16, 16, 8, 7, 7, 2>), dim3(3136), dim3(128), 0, stream,
                       poseP, aP, w1t, bu1, ba1, pose1, a1);
    // stage 2: N=144, C=16, 1600 positions, NW=4 (256 thr/block)
    hipLaunchKernelGGL((k_caps_split<144, 16, 3, 1, 7, 7, 16, 5, 5, 4>), dim3(1600), dim3(256), 0, stream,
                       pose1, a1, w2t, bu2, ba2, pose2, a2);
    // class: N=400, C=10, coords, BLK=1024
    hipLaunchKernelGGL((k_caps_class<400, 10, 5, 5, 16, 1024>), dim3(64), dim3(1024), 0, stream,
                       pose2, a2, wct, buc, bac, out);
}

// Round 8
// 251.010 us; speedup vs baseline: 1.1349x; 1.1349x over previous
//
#include <hip/hip_runtime.h>
#include <math.h>

#define EPS_ 1e-8f
#define LAM_ 1e-3f

// ---------------- K1: 5x5 conv s2 p2 + BN + ReLU ----------------
__global__ __launch_bounds__(256) void k_conv_bn(
    const float* __restrict__ x, const float* __restrict__ cw, const float* __restrict__ cb,
    const float* __restrict__ g, const float* __restrict__ bb,
    const float* __restrict__ mean, const float* __restrict__ var,
    float* __restrict__ y)
{
    int t = blockIdx.x * 256 + threadIdx.x;          // < 64*16*16*64
    int ch = t & 63, w = (t >> 6) & 15, h = (t >> 10) & 15, b = t >> 14;
    const float* xb = x + b * 1024;
    const float* wc = cw + ch * 25;
    float acc = cb[ch];
    #pragma unroll
    for (int kh = 0; kh < 5; ++kh) {
        int ih = h * 2 - 2 + kh;
        if (ih < 0 || ih > 31) continue;
        #pragma unroll
        for (int kw = 0; kw < 5; ++kw) {
            int iw = w * 2 - 2 + kw;
            if (iw < 0 || iw > 31) continue;
            acc = fmaf(xb[ih * 32 + iw], wc[kh * 5 + kw], acc);
        }
    }
    float v = (acc - mean[ch]) * (g[ch] * rsqrtf(var[ch] + 1e-3f)) + bb[ch];
    y[t] = fmaxf(v, 0.f);
}

// ---------------- K-prep: all weight transposes ----------------
__global__ __launch_bounds__(256) void k_transw(
    const float* __restrict__ w1, const float* __restrict__ w2, const float* __restrict__ wc,
    const float* __restrict__ pw, const float* __restrict__ pb,
    const float* __restrict__ aw, const float* __restrict__ ab,
    float* __restrict__ w1t, float* __restrict__ w2t, float* __restrict__ wct,
    float* __restrict__ wpt)
{
    int t = blockIdx.x * 256 + threadIdx.x;
    if (t < 3616 * 16) {
        int m = t >> 4, e = t & 15, r = e >> 2, q = e & 3;
        const float* src; float* dst;
        if (m < 1152)      { src = w1 + m * 16;          dst = w1t + m * 16; }
        else if (m < 3456) { src = w2 + (m - 1152) * 16; dst = w2t + (m - 1152) * 16; }
        else               { src = wc + (m - 3456) * 16; dst = wct + (m - 3456) * 16; }
        dst[e] = src[q * 4 + r];
    } else if (t < 3616 * 16 + 65 * 136) {
        int idx = t - 3616 * 16;
        int o = idx % 136, j = idx / 136;
        float v;
        if (j == 64)       v = (o < 128) ? pb[o] : ab[o - 128];
        else if (o < 128)  v = pw[o * 64 + j];
        else               v = aw[(o - 128) * 64 + j];
        wpt[j * 136 + o] = v;
    }
}

// ---------------- K2: primary caps (coalesced GEMM) ----------------
__global__ __launch_bounds__(256) void k_prim(
    const float* __restrict__ y, const float* __restrict__ wpt,
    float* __restrict__ poseP, float* __restrict__ aP)
{
    int t = blockIdx.x * 256 + threadIdx.x;
    if (t >= 16384 * 34) return;
    int oq = t % 34;
    int pos = t / 34;
    const float* yp = y + pos * 64;
    float4 acc = *(const float4*)(wpt + 64 * 136 + oq * 4);   // bias row
    #pragma unroll
    for (int j0 = 0; j0 < 64; j0 += 4) {
        float4 y4 = *(const float4*)(yp + j0);
        float4 w0 = *(const float4*)(wpt + (j0 + 0) * 136 + oq * 4);
        float4 w1 = *(const float4*)(wpt + (j0 + 1) * 136 + oq * 4);
        float4 w2 = *(const float4*)(wpt + (j0 + 2) * 136 + oq * 4);
        float4 w3 = *(const float4*)(wpt + (j0 + 3) * 136 + oq * 4);
        acc.x = fmaf(y4.x, w0.x, fmaf(y4.y, w1.x, fmaf(y4.z, w2.x, fmaf(y4.w, w3.x, acc.x))));
        acc.y = fmaf(y4.x, w0.y, fmaf(y4.y, w1.y, fmaf(y4.z, w2.y, fmaf(y4.w, w3.y, acc.y))));
        acc.z = fmaf(y4.x, w0.z, fmaf(y4.y, w1.z, fmaf(y4.z, w2.z, fmaf(y4.w, w3.z, acc.z))));
        acc.w = fmaf(y4.x, w0.w, fmaf(y4.y, w1.w, fmaf(y4.z, w2.w, fmaf(y4.w, w3.w, acc.w))));
    }
    if (oq < 32) {
        ((float4*)(poseP + pos * 128))[oq] = acc;
    } else {
        int oo = (oq - 32) * 4;
        float* ad = aP + pos * 8 + oo;
        ad[0] = 1.f / (1.f + __expf(-acc.x));
        ad[1] = 1.f / (1.f + __expf(-acc.y));
        ad[2] = 1.f / (1.f + __expf(-acc.z));
        ad[3] = 1.f / (1.f + __expf(-acc.w));
    }
}

// ---------------- split-wave capsule routing, G=2 positions per wave ----------------
// Block handles 2 positions; NW waves split the i-range. Each wave processes BOTH
// positions in its i-loop: the Wt row is loaded once per (i,cc) and reused, and the
// two positions' dist->rcp->shfl->rm chains are independent (intra-wave ILP).
template<int N, int C, int K, int S, int H, int W, int Bi, int OH, int OW, int NW>
__global__ __launch_bounds__(NW * 64) void k_caps_split2(
    const float* __restrict__ pose_in,  // (b,H,W,Bi,16)
    const float* __restrict__ a_in,     // (b,H,W,Bi)
    const float* __restrict__ Wt,       // (N,C,16) r-major transposed
    const float* __restrict__ bu, const float* __restrict__ ba,
    float* __restrict__ pose_out,       // (b,OH,OW,C,16)
    float* __restrict__ a_out)          // (b,OH,OW,C)
{
    static_assert(C == 16 && N % (NW * 4) == 0 && NW >= 2, "");
    constexpr int BLK = NW * 64;
    constexpr int IW  = N / NW;     // i's per wave
    constexpr int NIT = IW / 4;     // i's per thread

    __shared__ __align__(16) float pp[2][N * 16];
    __shared__ float ap[2][N];
    __shared__ __align__(16) float red1[NW][2][16][20];
    __shared__ __align__(16) float red2[NW][2][16][20];
    __shared__ float redr[NW][2][16];

    const int t = threadIdx.x;
    const int w = t >> 6, lane = t & 63;
    const int n0 = blockIdx.x * 2;

    int bb_[2], oh_[2], ow_[2];
    #pragma unroll
    for (int g = 0; g < 2; ++g) {
        int n_ = n0 + g;
        bb_[g] = n_ / (OH * OW);
        int rem = n_ % (OH * OW);
        oh_[g] = rem / OW; ow_[g] = rem % OW;
    }

    // ---- gather both positions' patch pose (float4) + activation into LDS ----
    for (int idx = t; idx < 2 * N * 4; idx += BLK) {
        int g = idx / (N * 4);
        int r2 = idx - g * (N * 4);
        int i = r2 >> 2, f = r2 & 3;
        int bi = i % Bi;
        int k2 = i / Bi;
        int sw = ow_[g] * S + (k2 % K), sh = oh_[g] * S + (k2 / K);
        const float4* src = (const float4*)(pose_in + (((bb_[g] * H + sh) * W + sw) * Bi + bi) * 16);
        ((float4*)(pp[g] + i * 16))[f] = src[f];
    }
    for (int idx = t; idx < 2 * N; idx += BLK) {
        int g = idx / N;
        int i = idx - g * N;
        int bi = i % Bi;
        int k2 = i / Bi;
        int sw = ow_[g] * S + (k2 % K), sh = oh_[g] * S + (k2 / K);
        ap[g][i] = a_in[((bb_[g] * H + sh) * W + sw) * Bi + bi];
    }
    __syncthreads();

    // ---- inv0 per position ----
    float s0A = 0.f, s0B = 0.f;
    for (int i = lane; i < N; i += 64) { s0A += ap[0][i]; s0B += ap[1][i]; }
    #pragma unroll
    for (int m = 1; m < 64; m <<= 1) { s0A += __shfl_xor(s0A, m, 64); s0B += __shfl_xor(s0B, m, 64); }
    const float inv0A = __builtin_amdgcn_rcpf(s0A + (float)(C * C) * EPS_);
    const float inv0B = __builtin_amdgcn_rcpf(s0B + (float)(C * C) * EPS_);

    const int ig = (lane >> 4) & 3, cc = lane & 15;
    const int ibase = w * IW;

    // ================= pass A: mu0 (both positions) =================
    float muA[16], muB[16];
    #pragma unroll
    for (int e2 = 0; e2 < 16; ++e2) { muA[e2] = 0.f; muB[e2] = 0.f; }
    for (int ii = 0; ii < NIT; ++ii) {
        int i = ibase + ig + ii * 4;
        const float4* wt4 = (const float4*)(Wt + (i * C + cc) * 16);
        float4 wv[4] = { wt4[0], wt4[1], wt4[2], wt4[3] };
        const float4* pA4 = (const float4*)(pp[0] + i * 16);
        const float4* pB4 = (const float4*)(pp[1] + i * 16);
        float4 pA[4] = { pA4[0], pA4[1], pA4[2], pA4[3] };
        float4 pB[4] = { pB4[0], pB4[1], pB4[2], pB4[3] };
        float coA = ap[0][i] * inv0A;
        float coB = ap[1][i] * inv0B;
        #pragma unroll
        for (int e2 = 0; e2 < 16; ++e2) {
            float4 w4 = wv[e2 & 3];
            float4 a4 = pA[e2 >> 2];
            float4 b4 = pB[e2 >> 2];
            float vA = a4.x * w4.x + a4.y * w4.y + a4.z * w4.z + a4.w * w4.w;
            float vB = b4.x * w4.x + b4.y * w4.y + b4.z * w4.z + b4.w * w4.w;
            muA[e2] = fmaf(coA, vA, muA[e2]);
            muB[e2] = fmaf(coB, vB, muB[e2]);
        }
    }
    #pragma unroll
    for (int e2 = 0; e2 < 16; ++e2) {
        muA[e2] += __shfl_xor(muA[e2], 16, 64);
        muA[e2] += __shfl_xor(muA[e2], 32, 64);
        muB[e2] += __shfl_xor(muB[e2], 16, 64);
        muB[e2] += __shfl_xor(muB[e2], 32, 64);
    }
    if (lane < 16) {
        float4* dA = (float4*)&red1[w][0][lane][0];
        float4* dB = (float4*)&red1[w][1][lane][0];
        dA[0] = *(float4*)&muA[0]; dA[1] = *(float4*)&muA[4];
        dA[2] = *(float4*)&muA[8]; dA[3] = *(float4*)&muA[12];
        dB[0] = *(float4*)&muB[0]; dB[1] = *(float4*)&muB[4];
        dB[2] = *(float4*)&muB[8]; dB[3] = *(float4*)&muB[12];
    }
    __syncthreads();

    float m0A[16], m0B[16];
    #pragma unroll
    for (int f = 0; f < 4; ++f) {
        float4 sA = *(const float4*)&red1[0][0][cc][f * 4];
        float4 sB = *(const float4*)&red1[0][1][cc][f * 4];
        #pragma unroll
        for (int ww = 1; ww < NW; ++ww) {
            float4 qA = *(const float4*)&red1[ww][0][cc][f * 4];
            float4 qB = *(const float4*)&red1[ww][1][cc][f * 4];
            sA.x += qA.x; sA.y += qA.y; sA.z += qA.z; sA.w += qA.w;
            sB.x += qB.x; sB.y += qB.y; sB.z += qB.z; sB.w += qB.w;
        }
        *(float4*)&m0A[f * 4] = sA;
        *(float4*)&m0B[f * 4] = sB;
    }
    __syncthreads();   // red1 reused below

    // ================= pass B: dist -> rm fused with Sv/Sv2/rsum (both positions) =================
    float SvA[16], Sv2A[16], SvB[16], Sv2B[16];
    #pragma unroll
    for (int e2 = 0; e2 < 16; ++e2) { SvA[e2] = 0.f; Sv2A[e2] = 0.f; SvB[e2] = 0.f; Sv2B[e2] = 0.f; }
    float rsA = 0.f, rsB = 0.f;
    for (int ii = 0; ii < NIT; ++ii) {
        int i = ibase + ig + ii * 4;
        const float4* wt4 = (const float4*)(Wt + (i * C + cc) * 16);
        float4 wv[4] = { wt4[0], wt4[1], wt4[2], wt4[3] };
        const float4* pA4 = (const float4*)(pp[0] + i * 16);
        const float4* pB4 = (const float4*)(pp[1] + i * 16);
        float4 pA[4] = { pA4[0], pA4[1], pA4[2], pA4[3] };
        float4 pB[4] = { pB4[0], pB4[1], pB4[2], pB4[3] };
        float vvA[16], vvB[16];
        float dA = EPS_, dB = EPS_;
        #pragma unroll
        for (int e2 = 0; e2 < 16; ++e2) {
            float4 w4 = wv[e2 & 3];
            float4 a4 = pA[e2 >> 2];
            float4 b4 = pB[e2 >> 2];
            float vA = a4.x * w4.x + a4.y * w4.y + a4.z * w4.z + a4.w * w4.w;
            float vB = b4.x * w4.x + b4.y * w4.y + b4.z * w4.z + b4.w * w4.w;
            vvA[e2] = vA; vvB[e2] = vB;
            float eA = vA - m0A[e2];
            float eB = vB - m0B[e2];
            dA = fmaf(eA, eA, dA);
            dB = fmaf(eB, eB, dB);
        }
        float invA = __builtin_amdgcn_rcpf(dA);
        float invB = __builtin_amdgcn_rcpf(dB);
        float sA = invA, sB = invB;
        #pragma unroll
        for (int m = 1; m < 16; m <<= 1) { sA += __shfl_xor(sA, m, 64); sB += __shfl_xor(sB, m, 64); }
        float r1A = invA * __builtin_amdgcn_rcpf(sA + EPS_);
        float r1B = invB * __builtin_amdgcn_rcpf(sB + EPS_);
        float rmA = r1A * r1A * ap[0][i];
        float rmB = r1B * r1B * ap[1][i];
        rsA += rmA; rsB += rmB;
        #pragma unroll
        for (int e2 = 0; e2 < 16; ++e2) {
            float rvA = rmA * vvA[e2];
            float rvB = rmB * vvB[e2];
            SvA[e2] += rvA;
            SvB[e2] += rvB;
            Sv2A[e2] = fmaf(rvA, vvA[e2], Sv2A[e2]);
            Sv2B[e2] = fmaf(rvB, vvB[e2], Sv2B[e2]);
        }
    }
    #pragma unroll
    for (int e2 = 0; e2 < 16; ++e2) {
        SvA[e2] += __shfl_xor(SvA[e2], 16, 64);  SvA[e2] += __shfl_xor(SvA[e2], 32, 64);
        Sv2A[e2] += __shfl_xor(Sv2A[e2], 16, 64); Sv2A[e2] += __shfl_xor(Sv2A[e2], 32, 64);
        SvB[e2] += __shfl_xor(SvB[e2], 16, 64);  SvB[e2] += __shfl_xor(SvB[e2], 32, 64);
        Sv2B[e2] += __shfl_xor(Sv2B[e2], 16, 64); Sv2B[e2] += __shfl_xor(Sv2B[e2], 32, 64);
    }
    rsA += __shfl_xor(rsA, 16, 64); rsA += __shfl_xor(rsA, 32, 64);
    rsB += __shfl_xor(rsB, 16, 64); rsB += __shfl_xor(rsB, 32, 64);
    if (lane < 16) {
        float4* d1A = (float4*)&red1[w][0][lane][0];
        float4* d2A = (float4*)&red2[w][0][lane][0];
        float4* d1B = (float4*)&red1[w][1][lane][0];
        float4* d2B = (float4*)&red2[w][1][lane][0];
        d1A[0] = *(float4*)&SvA[0];  d1A[1] = *(float4*)&SvA[4];
        d1A[2] = *(float4*)&SvA[8];  d1A[3] = *(float4*)&SvA[12];
        d2A[0] = *(float4*)&Sv2A[0]; d2A[1] = *(float4*)&Sv2A[4];
        d2A[2] = *(float4*)&Sv2A[8]; d2A[3] = *(float4*)&Sv2A[12];
        d1B[0] = *(float4*)&SvB[0];  d1B[1] = *(float4*)&SvB[4];
        d1B[2] = *(float4*)&SvB[8];  d1B[3] = *(float4*)&SvB[12];
        d2B[0] = *(float4*)&Sv2B[0]; d2B[1] = *(float4*)&Sv2B[4];
        d2B[2] = *(float4*)&Sv2B[8]; d2B[3] = *(float4*)&Sv2B[12];
        redr[w][0][lane] = rsA;
        redr[w][1][lane] = rsB;
    }
    __syncthreads();

    // ================= epilogue: wave g handles position g =================
    if (w < 2) {
        const int g = w;
        float SvT[16], Sv2T[16];
        #pragma unroll
        for (int f = 0; f < 4; ++f) {
            float4 s1 = *(const float4*)&red1[0][g][cc][f * 4];
            float4 s2 = *(const float4*)&red2[0][g][cc][f * 4];
            #pragma unroll
            for (int ww = 1; ww < NW; ++ww) {
                float4 p1 = *(const float4*)&red1[ww][g][cc][f * 4];
                float4 p2 = *(const float4*)&red2[ww][g][cc][f * 4];
                s1.x += p1.x; s1.y += p1.y; s1.z += p1.z; s1.w += p1.w;
                s2.x += p2.x; s2.y += p2.y; s2.z += p2.z; s2.w += p2.w;
            }
            *(float4*)&SvT[f * 4] = s1;
            *(float4*)&Sv2T[f * 4] = s2;
        }
        float R = 0.f;
        #pragma unroll
        for (int ww = 0; ww < NW; ++ww) R += redr[ww][g][cc];

        const float id = 1.f / (R + EPS_);
        const float S0 = R * id;
        const float buc_ = bu[cc];
        float cs = 0.f;
        float4 outv[4];
        #pragma unroll
        for (int e2 = 0; e2 < 16; ++e2) {
            float Sv = SvT[e2] * id;
            float Sv2 = Sv2T[e2] * id;
            float sigma = fmaxf(Sv2 + Sv * Sv * (S0 - 2.f), 0.f) + EPS_;
            cs += (buc_ + 0.5f * __logf(sigma)) * R;
            ((float*)outv)[e2] = Sv;
        }
        if (lane < 16) {
            int n_ = n0 + g;
            float4* pd = (float4*)(pose_out + (n_ * C + cc) * 16);
            pd[0] = outv[0]; pd[1] = outv[1]; pd[2] = outv[2]; pd[3] = outv[3];
            a_out[n_ * C + cc] = 1.f / (1.f + __expf(-(LAM_ * (ba[cc] - cs))));
        }
    }
}

// ---------------- block-wide caps (class layer, COORDS) ----------------
template<int N, int C, int H, int W, int Bi, int BLK>
__global__ __launch_bounds__(BLK) void k_caps_class(
    const float* __restrict__ pose_in, const float* __restrict__ a_in,
    const float* __restrict__ Wt,
    const float* __restrict__ bu, const float* __restrict__ ba,
    float* __restrict__ a_out)
{
    constexpr int NW  = BLK / 64;
    constexpr int NIG = BLK / 16;
    constexpr int NIT = (N + NIG - 1) / NIG;

    __shared__ __align__(16) float pp[N * 16];
    __shared__ float ap[N];
    __shared__ float coeff0[N];
    __shared__ float mu0[16 * 17];
    __shared__ float red1[NW * C * 17];
    __shared__ float red2[NW * C * 17];
    __shared__ float redr[NW * C];

    const int t = threadIdx.x;
    const int lane = t & 63;
    const int w = t >> 6;
    const int b = blockIdx.x;

    for (int idx = t; idx < N * 4; idx += BLK) {
        int i = idx >> 2, f = idx & 3;
        int bi = i % Bi;
        int hw = i / Bi;
        int sw = hw % W, sh = hw / W;
        const float4* src = (const float4*)(pose_in + (((b * H + sh) * W + sw) * Bi + bi) * 16);
        ((float4*)(pp + i * 16))[f] = src[f];
    }
    for (int i = t; i < N; i += BLK) {
        int bi = i % Bi;
        int hw = i / Bi;
        int sw = hw % W, sh = hw / W;
        ap[i] = a_in[((b * H + sh) * W + sw) * Bi + bi];
    }
    __syncthreads();

    {
        float part = 0.f;
        for (int i = t; i < N; i += BLK) part += ap[i];
        #pragma unroll
        for (int m = 1; m < 64; m <<= 1) part += __shfl_xor(part, m, 64);
        if (lane == 0) red1[w] = part;
        __syncthreads();
        float s = 0.f;
        #pragma unroll
        for (int ww = 0; ww < NW; ++ww) s += red1[ww];
        float inv0 = __builtin_amdgcn_rcpf(s + (float)(C * C) * EPS_);
        for (int i = t; i < N; i += BLK) coeff0[i] = ap[i] * inv0;
        __syncthreads();
    }

    const int ig = t >> 4, cc = t & 15;

    // pass A
    {
        float muU[16];
        #pragma unroll
        for (int e2 = 0; e2 < 16; ++e2) muU[e2] = 0.f;
        if (cc < C) {
            for (int ii = 0; ii < NIT; ++ii) {
                int i = ig + ii * NIG;
                if (i < N) {
                    const float4* pi4 = (const float4*)(pp + i * 16);
                    const float4* wt4 = (const float4*)(Wt + ((i % Bi) * C + cc) * 16);
                    float4 pv[4] = { pi4[0], pi4[1], pi4[2], pi4[3] };
                    float4 wv[4] = { wt4[0], wt4[1], wt4[2], wt4[3] };
                    float co = coeff0[i];
                    float chv = (float)(i / (W * Bi)) * (1.f / H);
                    float cwv = (float)((i / Bi) % W) * (1.f / W);
                    #pragma unroll
                    for (int e2 = 0; e2 < 16; ++e2) {
                        float4 p4 = pv[e2 >> 2], w4 = wv[e2 & 3];
                        float v = p4.x * w4.x + p4.y * w4.y + p4.z * w4.z + p4.w * w4.w;
                        if (e2 == 0) v += chv;
                        if (e2 == 1) v += cwv;
                        muU[e2] = fmaf(co, v, muU[e2]);
                    }
                }
            }
        }
        #pragma unroll
        for (int e2 = 0; e2 < 16; ++e2) {
            float xv = muU[e2];
            xv += __shfl_xor(xv, 16, 64);
            xv += __shfl_xor(xv, 32, 64);
            if (lane < 16 && lane < C) red1[(w * C + lane) * 17 + e2] = xv;
        }
        __syncthreads();
        if (t < 256) {
            int c = t >> 4, e = t & 15;
            if (c < C) {
                float m = 0.f;
                #pragma unroll
                for (int ww = 0; ww < NW; ++ww) m += red1[(ww * C + c) * 17 + e];
                mu0[c * 17 + e] = m;
            }
        }
        __syncthreads();
    }

    // pass B
    {
        float m0[16];
        if (cc < C) {
            #pragma unroll
            for (int e2 = 0; e2 < 16; ++e2) m0[e2] = mu0[cc * 17 + e2];
        }
        float SvU[16], Sv2U[16];
        #pragma unroll
        for (int e2 = 0; e2 < 16; ++e2) { SvU[e2] = 0.f; Sv2U[e2] = 0.f; }
        float rsumP = 0.f;

        for (int ii = 0; ii < NIT; ++ii) {
            int i = ig + ii * NIG;
            bool act = (i < N);
            float inv = 0.f;
            float vv[16];
            if (act && cc < C) {
                const float4* pi4 = (const float4*)(pp + i * 16);
                const float4* wt4 = (const float4*)(Wt + ((i % Bi) * C + cc) * 16);
                float4 pv[4] = { pi4[0], pi4[1], pi4[2], pi4[3] };
                float4 wv[4] = { wt4[0], wt4[1], wt4[2], wt4[3] };
                float chv = (float)(i / (W * Bi)) * (1.f / H);
                float cwv = (float)((i / Bi) % W) * (1.f / W);
                float dist = EPS_;
                #pragma unroll
                for (int e2 = 0; e2 < 16; ++e2) {
                    float4 p4 = pv[e2 >> 2], w4 = wv[e2 & 3];
                    float v = p4.x * w4.x + p4.y * w4.y + p4.z * w4.z + p4.w * w4.w;
                    if (e2 == 0) v += chv;
                    if (e2 == 1) v += cwv;
                    vv[e2] = v;
                    float d = v - m0[e2];
                    dist = fmaf(d, d, dist);
                }
                inv = __builtin_amdgcn_rcpf(dist);
            }
            float s = inv;
            #pragma unroll
            for (int m = 1; m < 16; m <<= 1) s += __shfl_xor(s, m, 64);
            if (act && cc < C) {
                float r1 = inv * __builtin_amdgcn_rcpf(s + EPS_);
                float rm = r1 * r1 * ap[i];
                rsumP += rm;
                #pragma unroll
                for (int e2 = 0; e2 < 16; ++e2) {
                    SvU[e2] = fmaf(rm, vv[e2], SvU[e2]);
                    Sv2U[e2] = fmaf(rm * vv[e2], vv[e2], Sv2U[e2]);
                }
            }
        }
        #pragma unroll
        for (int e2 = 0; e2 < 16; ++e2) {
            float xv = SvU[e2];
            xv += __shfl_xor(xv, 16, 64);
            xv += __shfl_xor(xv, 32, 64);
            float yv = Sv2U[e2];
            yv += __shfl_xor(yv, 16, 64);
            yv += __shfl_xor(yv, 32, 64);
            if (lane < 16 && lane < C) {
                red1[(w * C + lane) * 17 + e2] = xv;
                red2[(w * C + lane) * 17 + e2] = yv;
            }
        }
        {
            float rv = rsumP;
            rv += __shfl_xor(rv, 16, 64);
            rv += __shfl_xor(rv, 32, 64);
            if (lane < 16 && lane < C) redr[w * C + lane] = rv;
        }
        __syncthreads();
    }

    if (t < 256) {
        int c = t >> 4, e = t & 15;
        if (c < C) {
            float SvT = 0.f, Sv2T = 0.f, R = 0.f;
            #pragma unroll
            for (int ww = 0; ww < NW; ++ww) {
                SvT  += red1[(ww * C + c) * 17 + e];
                Sv2T += red2[(ww * C + c) * 17 + e];
                R    += redr[ww * C + c];
            }
            float id = 1.f / (R + EPS_);
            float S0 = R * id;
            float Sv = SvT * id;
            float Sv2 = Sv2T * id;
            float sigma = fmaxf(Sv2 + Sv * Sv * (S0 - 2.f), 0.f) + EPS_;
            float cost = (bu[c] + 0.5f * __logf(sigma)) * R;
            float cs = cost;
            #pragma unroll
            for (int m = 1; m < 16; m <<= 1) cs += __shfl_xor(cs, m, 64);
            if (e == 0) a_out[b * C + c] = 1.f / (1.f + __expf(-(LAM_ * (ba[c] - cs))));
        }
    }
}

extern "C" void kernel_launch(void* const* d_in, const int* in_sizes, int n_in,
                              void* d_out, int out_size, void* d_ws, size_t ws_size,
                              hipStream_t stream)
{
    const float* x   = (const float*)d_in[0];
    const float* c1w = (const float*)d_in[1];
    const float* c1b = (const float*)d_in[2];
    const float* bng = (const float*)d_in[3];
    const float* bnb = (const float*)d_in[4];
    const float* bnm = (const float*)d_in[5];
    const float* bnv = (const float*)d_in[6];
    const float* ppw = (const float*)d_in[7];
    const float* ppb = (const float*)d_in[8];
    const float* paw = (const float*)d_in[9];
    const float* pab = (const float*)d_in[10];
    const float* w1  = (const float*)d_in[11];
    const float* bu1 = (const float*)d_in[12];
    const float* ba1 = (const float*)d_in[13];
    const float* w2  = (const float*)d_in[14];
    const float* bu2 = (const float*)d_in[15];
    const float* ba2 = (const float*)d_in[16];
    const float* wcp = (const float*)d_in[17];
    const float* buc = (const float*)d_in[18];
    const float* bac = (const float*)d_in[19];
    float* out = (float*)d_out;

    float* ws    = (float*)d_ws;
    float* y     = ws;               // 64*16*16*64      = 1048576
    float* poseP = y + 1048576;      // 64*16*16*128     = 2097152
    float* aP    = poseP + 2097152;  // 64*16*16*8       = 131072
    float* pose1 = aP + 131072;      // 64*7*7*16*16     = 802816
    float* a1    = pose1 + 802816;   // 64*7*7*16        = 50176
    float* pose2 = a1 + 50176;       // 64*5*5*16*16     = 409600
    float* a2    = pose2 + 409600;   // 64*5*5*16        = 25600
    float* w1t   = a2 + 25600;       // 18432
    float* w2t   = w1t + 18432;      // 36864
    float* wct   = w2t + 36864;      // 2560
    float* wpt   = wct + 2560;       // 65*136 = 8840

    hipLaunchKernelGGL(k_transw, dim3((3616 * 16 + 65 * 136 + 255) / 256), dim3(256), 0, stream,
                       w1, w2, wcp, ppw, ppb, paw, pab, w1t, w2t, wct, wpt);
    hipLaunchKernelGGL(k_conv_bn, dim3(4096), dim3(256), 0, stream,
                       x, c1w, c1b, bng, bnb, bnm, bnv, y);
    hipLaunchKernelGGL(k_prim, dim3((16384 * 34 + 255) / 256), dim3(256), 0, stream,
                       y, wpt, poseP, aP);
    // stage 1: N=72, 3136 positions -> 1568 blocks x (NW=2 waves, G=2 positions)
    hipLaunchKernelGGL((k_caps_split2<72, 16, 3, 2, 16, 16, 8, 7, 7, 2>), dim3(1568), dim3(128), 0, stream,
                       poseP, aP, w1t, bu1, ba1, pose1, a1);
    // stage 2: N=144, 1600 positions -> 800 blocks x (NW=2 waves, G=2 positions)
    hipLaunchKernelGGL((k_caps_split2<144, 16, 3, 1, 7, 7, 16, 5, 5, 2>), dim3(800), dim3(128), 0, stream,
                       pose1, a1, w2t, bu2, ba2, pose2, a2);
    // class: N=400, C=10, coords, BLK=1024
    hipLaunchKernelGGL((k_caps_class<400, 10, 5, 5, 16, 1024>), dim3(64), dim3(1024), 0, stream,
                       pose2, a2, wct, buc, bac, out);
}

// Round 9
// 246.874 us; speedup vs baseline: 1.1539x; 1.0168x over previous
//
#include <hip/hip_runtime.h>
#include <math.h>

#define EPS_ 1e-8f
#define LAM_ 1e-3f

// ---------------- K1: 5x5 conv s2 p2 + BN + ReLU, fused with weight transposes ----------------
// blocks [0,4096): conv+bn+relu.  blocks [4096, 4096+261): weight transposes.
__global__ __launch_bounds__(256) void k_conv_transw(
    const float* __restrict__ x, const float* __restrict__ cw, const float* __restrict__ cb,
    const float* __restrict__ g, const float* __restrict__ bb,
    const float* __restrict__ mean, const float* __restrict__ var,
    float* __restrict__ y,
    const float* __restrict__ w1, const float* __restrict__ w2, const float* __restrict__ wc,
    const float* __restrict__ pw, const float* __restrict__ pb,
    const float* __restrict__ aw, const float* __restrict__ ab,
    float* __restrict__ w1t, float* __restrict__ w2t, float* __restrict__ wct,
    float* __restrict__ wpt)
{
    if (blockIdx.x < 4096) {
        int t = blockIdx.x * 256 + threadIdx.x;          // < 64*16*16*64
        int ch = t & 63, w = (t >> 6) & 15, h = (t >> 10) & 15, b = t >> 14;
        const float* xb = x + b * 1024;
        const float* wc_ = cw + ch * 25;
        float acc = cb[ch];
        #pragma unroll
        for (int kh = 0; kh < 5; ++kh) {
            int ih = h * 2 - 2 + kh;
            if (ih < 0 || ih > 31) continue;
            #pragma unroll
            for (int kw = 0; kw < 5; ++kw) {
                int iw = w * 2 - 2 + kw;
                if (iw < 0 || iw > 31) continue;
                acc = fmaf(xb[ih * 32 + iw], wc_[kh * 5 + kw], acc);
            }
        }
        float v = (acc - mean[ch]) * (g[ch] * rsqrtf(var[ch] + 1e-3f)) + bb[ch];
        y[t] = fmaxf(v, 0.f);
    } else {
        int t = (blockIdx.x - 4096) * 256 + threadIdx.x;
        if (t < 3616 * 16) {
            int m = t >> 4, e = t & 15, r = e >> 2, q = e & 3;
            const float* src; float* dst;
            if (m < 1152)      { src = w1 + m * 16;          dst = w1t + m * 16; }
            else if (m < 3456) { src = w2 + (m - 1152) * 16; dst = w2t + (m - 1152) * 16; }
            else               { src = wc + (m - 3456) * 16; dst = wct + (m - 3456) * 16; }
            dst[e] = src[q * 4 + r];
        } else if (t < 3616 * 16 + 65 * 136) {
            int idx = t - 3616 * 16;
            int o = idx % 136, j = idx / 136;
            float v;
            if (j == 64)       v = (o < 128) ? pb[o] : ab[o - 128];
            else if (o < 128)  v = pw[o * 64 + j];
            else               v = aw[(o - 128) * 64 + j];
            wpt[j * 136 + o] = v;
        }
    }
}

// ---------------- K2: primary caps (coalesced GEMM) ----------------
__global__ __launch_bounds__(256) void k_prim(
    const float* __restrict__ y, const float* __restrict__ wpt,
    float* __restrict__ poseP, float* __restrict__ aP)
{
    int t = blockIdx.x * 256 + threadIdx.x;
    if (t >= 16384 * 34) return;
    int oq = t % 34;
    int pos = t / 34;
    const float* yp = y + pos * 64;
    float4 acc = *(const float4*)(wpt + 64 * 136 + oq * 4);   // bias row
    #pragma unroll
    for (int j0 = 0; j0 < 64; j0 += 4) {
        float4 y4 = *(const float4*)(yp + j0);
        float4 w0 = *(const float4*)(wpt + (j0 + 0) * 136 + oq * 4);
        float4 w1 = *(const float4*)(wpt + (j0 + 1) * 136 + oq * 4);
        float4 w2 = *(const float4*)(wpt + (j0 + 2) * 136 + oq * 4);
        float4 w3 = *(const float4*)(wpt + (j0 + 3) * 136 + oq * 4);
        acc.x = fmaf(y4.x, w0.x, fmaf(y4.y, w1.x, fmaf(y4.z, w2.x, fmaf(y4.w, w3.x, acc.x))));
        acc.y = fmaf(y4.x, w0.y, fmaf(y4.y, w1.y, fmaf(y4.z, w2.y, fmaf(y4.w, w3.y, acc.y))));
        acc.z = fmaf(y4.x, w0.z, fmaf(y4.y, w1.z, fmaf(y4.z, w2.z, fmaf(y4.w, w3.z, acc.z))));
        acc.w = fmaf(y4.x, w0.w, fmaf(y4.y, w1.w, fmaf(y4.z, w2.w, fmaf(y4.w, w3.w, acc.w))));
    }
    if (oq < 32) {
        ((float4*)(poseP + pos * 128))[oq] = acc;
    } else {
        int oo = (oq - 32) * 4;
        float* ad = aP + pos * 8 + oo;
        ad[0] = 1.f / (1.f + __expf(-acc.x));
        ad[1] = 1.f / (1.f + __expf(-acc.y));
        ad[2] = 1.f / (1.f + __expf(-acc.z));
        ad[3] = 1.f / (1.f + __expf(-acc.w));
    }
}

// ---------------- split-wave capsule routing, G=2 positions/wave, SW-pipelined ----------------
// Iteration k+1's operands are prefetched into registers BEFORE iteration k's shuffle
// chain, so global/LDS load latency overlaps the ds_swizzle latency instead of adding.
template<int N, int C, int K, int S, int H, int W, int Bi, int OH, int OW, int NW>
__global__ __launch_bounds__(NW * 64) void k_caps_split2(
    const float* __restrict__ pose_in,  // (b,H,W,Bi,16)
    const float* __restrict__ a_in,     // (b,H,W,Bi)
    const float* __restrict__ Wt,       // (N,C,16) r-major transposed
    const float* __restrict__ bu, const float* __restrict__ ba,
    float* __restrict__ pose_out,       // (b,OH,OW,C,16)
    float* __restrict__ a_out)          // (b,OH,OW,C)
{
    static_assert(C == 16 && N % (NW * 4) == 0 && NW >= 2, "");
    constexpr int BLK = NW * 64;
    constexpr int IW  = N / NW;     // i's per wave
    constexpr int NIT = IW / 4;     // i's per thread

    __shared__ __align__(16) float pp[2][N * 16];
    __shared__ float ap[2][N];
    __shared__ __align__(16) float red1[NW][2][16][20];
    __shared__ __align__(16) float red2[NW][2][16][20];
    __shared__ float redr[NW][2][16];

    const int t = threadIdx.x;
    const int w = t >> 6, lane = t & 63;
    const int n0 = blockIdx.x * 2;

    int bb_[2], oh_[2], ow_[2];
    #pragma unroll
    for (int g = 0; g < 2; ++g) {
        int n_ = n0 + g;
        bb_[g] = n_ / (OH * OW);
        int rem = n_ % (OH * OW);
        oh_[g] = rem / OW; ow_[g] = rem % OW;
    }

    // ---- gather both positions' patch pose (float4) + activation into LDS ----
    for (int idx = t; idx < 2 * N * 4; idx += BLK) {
        int g = idx / (N * 4);
        int r2 = idx - g * (N * 4);
        int i = r2 >> 2, f = r2 & 3;
        int bi = i % Bi;
        int k2 = i / Bi;
        int sw = ow_[g] * S + (k2 % K), sh = oh_[g] * S + (k2 / K);
        const float4* src = (const float4*)(pose_in + (((bb_[g] * H + sh) * W + sw) * Bi + bi) * 16);
        ((float4*)(pp[g] + i * 16))[f] = src[f];
    }
    for (int idx = t; idx < 2 * N; idx += BLK) {
        int g = idx / N;
        int i = idx - g * N;
        int bi = i % Bi;
        int k2 = i / Bi;
        int sw = ow_[g] * S + (k2 % K), sh = oh_[g] * S + (k2 / K);
        ap[g][i] = a_in[((bb_[g] * H + sh) * W + sw) * Bi + bi];
    }
    __syncthreads();

    // ---- inv0 per position ----
    float s0A = 0.f, s0B = 0.f;
    for (int i = lane; i < N; i += 64) { s0A += ap[0][i]; s0B += ap[1][i]; }
    #pragma unroll
    for (int m = 1; m < 64; m <<= 1) { s0A += __shfl_xor(s0A, m, 64); s0B += __shfl_xor(s0B, m, 64); }
    const float inv0A = __builtin_amdgcn_rcpf(s0A + (float)(C * C) * EPS_);
    const float inv0B = __builtin_amdgcn_rcpf(s0B + (float)(C * C) * EPS_);

    const int ig = (lane >> 4) & 3, cc = lane & 15;
    const int ibase = w * IW;

    // ================= pass A: mu0 (both positions, fully prefetched) =================
    float muA[16], muB[16];
    #pragma unroll
    for (int e2 = 0; e2 < 16; ++e2) { muA[e2] = 0.f; muB[e2] = 0.f; }
    float4 wv[4], pA[4], pB[4];
    float apA, apB;
    {
        int i0 = ibase + ig;
        const float4* wt4 = (const float4*)(Wt + (i0 * C + cc) * 16);
        const float4* pA4 = (const float4*)(pp[0] + i0 * 16);
        const float4* pB4 = (const float4*)(pp[1] + i0 * 16);
        wv[0] = wt4[0]; wv[1] = wt4[1]; wv[2] = wt4[2]; wv[3] = wt4[3];
        pA[0] = pA4[0]; pA[1] = pA4[1]; pA[2] = pA4[2]; pA[3] = pA4[3];
        pB[0] = pB4[0]; pB[1] = pB4[1]; pB[2] = pB4[2]; pB[3] = pB4[3];
        apA = ap[0][i0]; apB = ap[1][i0];
    }
    for (int ii = 0; ii < NIT; ++ii) {
        float4 nwv[4], npA[4], npB[4];
        float napA = 0.f, napB = 0.f;
        if (ii + 1 < NIT) {
            int j = ibase + ig + (ii + 1) * 4;
            const float4* wt4 = (const float4*)(Wt + (j * C + cc) * 16);
            const float4* pA4 = (const float4*)(pp[0] + j * 16);
            const float4* pB4 = (const float4*)(pp[1] + j * 16);
            nwv[0] = wt4[0]; nwv[1] = wt4[1]; nwv[2] = wt4[2]; nwv[3] = wt4[3];
            npA[0] = pA4[0]; npA[1] = pA4[1]; npA[2] = pA4[2]; npA[3] = pA4[3];
            npB[0] = pB4[0]; npB[1] = pB4[1]; npB[2] = pB4[2]; npB[3] = pB4[3];
            napA = ap[0][j]; napB = ap[1][j];
        } else {
            nwv[0] = nwv[1] = nwv[2] = nwv[3] = make_float4(0, 0, 0, 0);
            npA[0] = npA[1] = npA[2] = npA[3] = make_float4(0, 0, 0, 0);
            npB[0] = npB[1] = npB[2] = npB[3] = make_float4(0, 0, 0, 0);
        }
        float coA = apA * inv0A;
        float coB = apB * inv0B;
        #pragma unroll
        for (int e2 = 0; e2 < 16; ++e2) {
            float4 w4 = wv[e2 & 3];
            float4 a4 = pA[e2 >> 2];
            float4 b4 = pB[e2 >> 2];
            float vA = a4.x * w4.x + a4.y * w4.y + a4.z * w4.z + a4.w * w4.w;
            float vB = b4.x * w4.x + b4.y * w4.y + b4.z * w4.z + b4.w * w4.w;
            muA[e2] = fmaf(coA, vA, muA[e2]);
            muB[e2] = fmaf(coB, vB, muB[e2]);
        }
        #pragma unroll
        for (int f = 0; f < 4; ++f) { wv[f] = nwv[f]; pA[f] = npA[f]; pB[f] = npB[f]; }
        apA = napA; apB = napB;
    }
    #pragma unroll
    for (int e2 = 0; e2 < 16; ++e2) {
        muA[e2] += __shfl_xor(muA[e2], 16, 64);
        muA[e2] += __shfl_xor(muA[e2], 32, 64);
        muB[e2] += __shfl_xor(muB[e2], 16, 64);
        muB[e2] += __shfl_xor(muB[e2], 32, 64);
    }
    if (lane < 16) {
        float4* dA = (float4*)&red1[w][0][lane][0];
        float4* dB = (float4*)&red1[w][1][lane][0];
        dA[0] = *(float4*)&muA[0]; dA[1] = *(float4*)&muA[4];
        dA[2] = *(float4*)&muA[8]; dA[3] = *(float4*)&muA[12];
        dB[0] = *(float4*)&muB[0]; dB[1] = *(float4*)&muB[4];
        dB[2] = *(float4*)&muB[8]; dB[3] = *(float4*)&muB[12];
    }
    __syncthreads();

    float m0A[16], m0B[16];
    #pragma unroll
    for (int f = 0; f < 4; ++f) {
        float4 sA = *(const float4*)&red1[0][0][cc][f * 4];
        float4 sB = *(const float4*)&red1[0][1][cc][f * 4];
        #pragma unroll
        for (int ww = 1; ww < NW; ++ww) {
            float4 qA = *(const float4*)&red1[ww][0][cc][f * 4];
            float4 qB = *(const float4*)&red1[ww][1][cc][f * 4];
            sA.x += qA.x; sA.y += qA.y; sA.z += qA.z; sA.w += qA.w;
            sB.x += qB.x; sB.y += qB.y; sB.z += qB.z; sB.w += qB.w;
        }
        *(float4*)&m0A[f * 4] = sA;
        *(float4*)&m0B[f * 4] = sB;
    }
    __syncthreads();   // red1 reused below

    // ================= pass B: dist -> rm fused with Sv/Sv2/rsum (Wt prefetched) =================
    float SvA[16], Sv2A[16], SvB[16], Sv2B[16];
    #pragma unroll
    for (int e2 = 0; e2 < 16; ++e2) { SvA[e2] = 0.f; Sv2A[e2] = 0.f; SvB[e2] = 0.f; Sv2B[e2] = 0.f; }
    float rsA = 0.f, rsB = 0.f;
    {
        int i0 = ibase + ig;
        const float4* wt4 = (const float4*)(Wt + (i0 * C + cc) * 16);
        wv[0] = wt4[0]; wv[1] = wt4[1]; wv[2] = wt4[2]; wv[3] = wt4[3];
    }
    for (int ii = 0; ii < NIT; ++ii) {
        int i = ibase + ig + ii * 4;
        float4 nwv[4];
        if (ii + 1 < NIT) {
            const float4* wt4 = (const float4*)(Wt + ((i + 4) * C + cc) * 16);
            nwv[0] = wt4[0]; nwv[1] = wt4[1]; nwv[2] = wt4[2]; nwv[3] = wt4[3];
        } else {
            nwv[0] = nwv[1] = nwv[2] = nwv[3] = make_float4(0, 0, 0, 0);
        }
        const float4* pA4 = (const float4*)(pp[0] + i * 16);
        const float4* pB4 = (const float4*)(pp[1] + i * 16);
        float4 pAv[4] = { pA4[0], pA4[1], pA4[2], pA4[3] };
        float4 pBv[4] = { pB4[0], pB4[1], pB4[2], pB4[3] };
        float vvA[16], vvB[16];
        float dA = EPS_, dB = EPS_;
        #pragma unroll
        for (int e2 = 0; e2 < 16; ++e2) {
            float4 w4 = wv[e2 & 3];
            float4 a4 = pAv[e2 >> 2];
            float4 b4 = pBv[e2 >> 2];
            float vA = a4.x * w4.x + a4.y * w4.y + a4.z * w4.z + a4.w * w4.w;
            float vB = b4.x * w4.x + b4.y * w4.y + b4.z * w4.z + b4.w * w4.w;
            vvA[e2] = vA; vvB[e2] = vB;
            float eA = vA - m0A[e2];
            float eB = vB - m0B[e2];
            dA = fmaf(eA, eA, dA);
            dB = fmaf(eB, eB, dB);
        }
        float invA = __builtin_amdgcn_rcpf(dA);
        float invB = __builtin_amdgcn_rcpf(dB);
        float sA = invA, sB = invB;
        #pragma unroll
        for (int m = 1; m < 16; m <<= 1) { sA += __shfl_xor(sA, m, 64); sB += __shfl_xor(sB, m, 64); }
        float r1A = invA * __builtin_amdgcn_rcpf(sA + EPS_);
        float r1B = invB * __builtin_amdgcn_rcpf(sB + EPS_);
        float rmA = r1A * r1A * ap[0][i];
        float rmB = r1B * r1B * ap[1][i];
        rsA += rmA; rsB += rmB;
        #pragma unroll
        for (int e2 = 0; e2 < 16; ++e2) {
            float rvA = rmA * vvA[e2];
            float rvB = rmB * vvB[e2];
            SvA[e2] += rvA;
            SvB[e2] += rvB;
            Sv2A[e2] = fmaf(rvA, vvA[e2], Sv2A[e2]);
            Sv2B[e2] = fmaf(rvB, vvB[e2], Sv2B[e2]);
        }
        #pragma unroll
        for (int f = 0; f < 4; ++f) wv[f] = nwv[f];
    }
    #pragma unroll
    for (int e2 = 0; e2 < 16; ++e2) {
        SvA[e2] += __shfl_xor(SvA[e2], 16, 64);  SvA[e2] += __shfl_xor(SvA[e2], 32, 64);
        Sv2A[e2] += __shfl_xor(Sv2A[e2], 16, 64); Sv2A[e2] += __shfl_xor(Sv2A[e2], 32, 64);
        SvB[e2] += __shfl_xor(SvB[e2], 16, 64);  SvB[e2] += __shfl_xor(SvB[e2], 32, 64);
        Sv2B[e2] += __shfl_xor(Sv2B[e2], 16, 64); Sv2B[e2] += __shfl_xor(Sv2B[e2], 32, 64);
    }
    rsA += __shfl_xor(rsA, 16, 64); rsA += __shfl_xor(rsA, 32, 64);
    rsB += __shfl_xor(rsB, 16, 64); rsB += __shfl_xor(rsB, 32, 64);
    if (lane < 16) {
        float4* d1A = (float4*)&red1[w][0][lane][0];
        float4* d2A = (float4*)&red2[w][0][lane][0];
        float4* d1B = (float4*)&red1[w][1][lane][0];
        float4* d2B = (float4*)&red2[w][1][lane][0];
        d1A[0] = *(float4*)&SvA[0];  d1A[1] = *(float4*)&SvA[4];
        d1A[2] = *(float4*)&SvA[8];  d1A[3] = *(float4*)&SvA[12];
        d2A[0] = *(float4*)&Sv2A[0]; d2A[1] = *(float4*)&Sv2A[4];
        d2A[2] = *(float4*)&Sv2A[8]; d2A[3] = *(float4*)&Sv2A[12];
        d1B[0] = *(float4*)&SvB[0];  d1B[1] = *(float4*)&SvB[4];
        d1B[2] = *(float4*)&SvB[8];  d1B[3] = *(float4*)&SvB[12];
        d2B[0] = *(float4*)&Sv2B[0]; d2B[1] = *(float4*)&Sv2B[4];
        d2B[2] = *(float4*)&Sv2B[8]; d2B[3] = *(float4*)&Sv2B[12];
        redr[w][0][lane] = rsA;
        redr[w][1][lane] = rsB;
    }
    __syncthreads();

    // ================= epilogue: wave g handles position g =================
    if (w < 2) {
        const int g = w;
        float SvT[16], Sv2T[16];
        #pragma unroll
        for (int f = 0; f < 4; ++f) {
            float4 s1 = *(const float4*)&red1[0][g][cc][f * 4];
            float4 s2 = *(const float4*)&red2[0][g][cc][f * 4];
            #pragma unroll
            for (int ww = 1; ww < NW; ++ww) {
                float4 p1 = *(const float4*)&red1[ww][g][cc][f * 4];
                float4 p2 = *(const float4*)&red2[ww][g][cc][f * 4];
                s1.x += p1.x; s1.y += p1.y; s1.z += p1.z; s1.w += p1.w;
                s2.x += p2.x; s2.y += p2.y; s2.z += p2.z; s2.w += p2.w;
            }
            *(float4*)&SvT[f * 4] = s1;
            *(float4*)&Sv2T[f * 4] = s2;
        }
        float R = 0.f;
        #pragma unroll
        for (int ww = 0; ww < NW; ++ww) R += redr[ww][g][cc];

        const float id = 1.f / (R + EPS_);
        const float S0 = R * id;
        const float buc_ = bu[cc];
        float cs = 0.f;
        float4 outv[4];
        #pragma unroll
        for (int e2 = 0; e2 < 16; ++e2) {
            float Sv = SvT[e2] * id;
            float Sv2 = Sv2T[e2] * id;
            float sigma = fmaxf(Sv2 + Sv * Sv * (S0 - 2.f), 0.f) + EPS_;
            cs += (buc_ + 0.5f * __logf(sigma)) * R;
            ((float*)outv)[e2] = Sv;
        }
        if (lane < 16) {
            int n_ = n0 + g;
            float4* pd = (float4*)(pose_out + (n_ * C + cc) * 16);
            pd[0] = outv[0]; pd[1] = outv[1]; pd[2] = outv[2]; pd[3] = outv[3];
            a_out[n_ * C + cc] = 1.f / (1.f + __expf(-(LAM_ * (ba[cc] - cs))));
        }
    }
}

// ---------------- block-wide caps (class layer, COORDS) ----------------
template<int N, int C, int H, int W, int Bi, int BLK>
__global__ __launch_bounds__(BLK) void k_caps_class(
    const float* __restrict__ pose_in, const float* __restrict__ a_in,
    const float* __restrict__ Wt,
    const float* __restrict__ bu, const float* __restrict__ ba,
    float* __restrict__ a_out)
{
    constexpr int NW  = BLK / 64;
    constexpr int NIG = BLK / 16;
    constexpr int NIT = (N + NIG - 1) / NIG;

    __shared__ __align__(16) float pp[N * 16];
    __shared__ float ap[N];
    __shared__ float coeff0[N];
    __shared__ float mu0[16 * 17];
    __shared__ float red1[NW * C * 17];
    __shared__ float red2[NW * C * 17];
    __shared__ float redr[NW * C];

    const int t = threadIdx.x;
    const int lane = t & 63;
    const int w = t >> 6;
    const int b = blockIdx.x;

    for (int idx = t; idx < N * 4; idx += BLK) {
        int i = idx >> 2, f = idx & 3;
        int bi = i % Bi;
        int hw = i / Bi;
        int sw = hw % W, sh = hw / W;
        const float4* src = (const float4*)(pose_in + (((b * H + sh) * W + sw) * Bi + bi) * 16);
        ((float4*)(pp + i * 16))[f] = src[f];
    }
    for (int i = t; i < N; i += BLK) {
        int bi = i % Bi;
        int hw = i / Bi;
        int sw = hw % W, sh = hw / W;
        ap[i] = a_in[((b * H + sh) * W + sw) * Bi + bi];
    }
    __syncthreads();

    {
        float part = 0.f;
        for (int i = t; i < N; i += BLK) part += ap[i];
        #pragma unroll
        for (int m = 1; m < 64; m <<= 1) part += __shfl_xor(part, m, 64);
        if (lane == 0) red1[w] = part;
        __syncthreads();
        float s = 0.f;
        #pragma unroll
        for (int ww = 0; ww < NW; ++ww) s += red1[ww];
        float inv0 = __builtin_amdgcn_rcpf(s + (float)(C * C) * EPS_);
        for (int i = t; i < N; i += BLK) coeff0[i] = ap[i] * inv0;
        __syncthreads();
    }

    const int ig = t >> 4, cc = t & 15;

    // pass A
    {
        float muU[16];
        #pragma unroll
        for (int e2 = 0; e2 < 16; ++e2) muU[e2] = 0.f;
        if (cc < C) {
            for (int ii = 0; ii < NIT; ++ii) {
                int i = ig + ii * NIG;
                if (i < N) {
                    const float4* pi4 = (const float4*)(pp + i * 16);
                    const float4* wt4 = (const float4*)(Wt + ((i % Bi) * C + cc) * 16);
                    float4 pv[4] = { pi4[0], pi4[1], pi4[2], pi4[3] };
                    float4 wv[4] = { wt4[0], wt4[1], wt4[2], wt4[3] };
                    float co = coeff0[i];
                    float chv = (float)(i / (W * Bi)) * (1.f / H);
                    float cwv = (float)((i / Bi) % W) * (1.f / W);
                    #pragma unroll
                    for (int e2 = 0; e2 < 16; ++e2) {
                        float4 p4 = pv[e2 >> 2], w4 = wv[e2 & 3];
                        float v = p4.x * w4.x + p4.y * w4.y + p4.z * w4.z + p4.w * w4.w;
                        if (e2 == 0) v += chv;
                        if (e2 == 1) v += cwv;
                        muU[e2] = fmaf(co, v, muU[e2]);
                    }
                }
            }
        }
        #pragma unroll
        for (int e2 = 0; e2 < 16; ++e2) {
            float xv = muU[e2];
            xv += __shfl_xor(xv, 16, 64);
            xv += __shfl_xor(xv, 32, 64);
            if (lane < 16 && lane < C) red1[(w * C + lane) * 17 + e2] = xv;
        }
        __syncthreads();
        if (t < 256) {
            int c = t >> 4, e = t & 15;
            if (c < C) {
                float m = 0.f;
                #pragma unroll
                for (int ww = 0; ww < NW; ++ww) m += red1[(ww * C + c) * 17 + e];
                mu0[c * 17 + e] = m;
            }
        }
        __syncthreads();
    }

    // pass B
    {
        float m0[16];
        if (cc < C) {
            #pragma unroll
            for (int e2 = 0; e2 < 16; ++e2) m0[e2] = mu0[cc * 17 + e2];
        }
        float SvU[16], Sv2U[16];
        #pragma unroll
        for (int e2 = 0; e2 < 16; ++e2) { SvU[e2] = 0.f; Sv2U[e2] = 0.f; }
        float rsumP = 0.f;

        for (int ii = 0; ii < NIT; ++ii) {
            int i = ig + ii * NIG;
            bool act = (i < N);
            float inv = 0.f;
            float vv[16];
            if (act && cc < C) {
                const float4* pi4 = (const float4*)(pp + i * 16);
                const float4* wt4 = (const float4*)(Wt + ((i % Bi) * C + cc) * 16);
                float4 pv[4] = { pi4[0], pi4[1], pi4[2], pi4[3] };
                float4 wv[4] = { wt4[0], wt4[1], wt4[2], wt4[3] };
                float chv = (float)(i / (W * Bi)) * (1.f / H);
                float cwv = (float)((i / Bi) % W) * (1.f / W);
                float dist = EPS_;
                #pragma unroll
                for (int e2 = 0; e2 < 16; ++e2) {
                    float4 p4 = pv[e2 >> 2], w4 = wv[e2 & 3];
                    float v = p4.x * w4.x + p4.y * w4.y + p4.z * w4.z + p4.w * w4.w;
                    if (e2 == 0) v += chv;
                    if (e2 == 1) v += cwv;
                    vv[e2] = v;
                    float d = v - m0[e2];
                    dist = fmaf(d, d, dist);
                }
                inv = __builtin_amdgcn_rcpf(dist);
            }
            float s = inv;
            #pragma unroll
            for (int m = 1; m < 16; m <<= 1) s += __shfl_xor(s, m, 64);
            if (act && cc < C) {
                float r1 = inv * __builtin_amdgcn_rcpf(s + EPS_);
                float rm = r1 * r1 * ap[i];
                rsumP += rm;
                #pragma unroll
                for (int e2 = 0; e2 < 16; ++e2) {
                    SvU[e2] = fmaf(rm, vv[e2], SvU[e2]);
                    Sv2U[e2] = fmaf(rm * vv[e2], vv[e2], Sv2U[e2]);
                }
            }
        }
        #pragma unroll
        for (int e2 = 0; e2 < 16; ++e2) {
            float xv = SvU[e2];
            xv += __shfl_xor(xv, 16, 64);
            xv += __shfl_xor(xv, 32, 64);
            float yv = Sv2U[e2];
            yv += __shfl_xor(yv, 16, 64);
            yv += __shfl_xor(yv, 32, 64);
            if (lane < 16 && lane < C) {
                red1[(w * C + lane) * 17 + e2] = xv;
                red2[(w * C + lane) * 17 + e2] = yv;
            }
        }
        {
            float rv = rsumP;
            rv += __shfl_xor(rv, 16, 64);
            rv += __shfl_xor(rv, 32, 64);
            if (lane < 16 && lane < C) redr[w * C + lane] = rv;
        }
        __syncthreads();
    }

    if (t < 256) {
        int c = t >> 4, e = t & 15;
        if (c < C) {
            float SvT = 0.f, Sv2T = 0.f, R = 0.f;
            #pragma unroll
            for (int ww = 0; ww < NW; ++ww) {
                SvT  += red1[(ww * C + c) * 17 + e];
                Sv2T += red2[(ww * C + c) * 17 + e];
                R    += redr[ww * C + c];
            }
            float id = 1.f / (R + EPS_);
            float S0 = R * id;
            float Sv = SvT * id;
            float Sv2 = Sv2T * id;
            float sigma = fmaxf(Sv2 + Sv * Sv * (S0 - 2.f), 0.f) + EPS_;
            float cost = (bu[c] + 0.5f * __logf(sigma)) * R;
            float cs = cost;
            #pragma unroll
            for (int m = 1; m < 16; m <<= 1) cs += __shfl_xor(cs, m, 64);
            if (e == 0) a_out[b * C + c] = 1.f / (1.f + __expf(-(LAM_ * (ba[c] - cs))));
        }
    }
}

extern "C" void kernel_launch(void* const* d_in, const int* in_sizes, int n_in,
                              void* d_out, int out_size, void* d_ws, size_t ws_size,
                              hipStream_t stream)
{
    const float* x   = (const float*)d_in[0];
    const float* c1w = (const float*)d_in[1];
    const float* c1b = (const float*)d_in[2];
    const float* bng = (const float*)d_in[3];
    const float* bnb = (const float*)d_in[4];
    const float* bnm = (const float*)d_in[5];
    const float* bnv = (const float*)d_in[6];
    const float* ppw = (const float*)d_in[7];
    const float* ppb = (const float*)d_in[8];
    const float* paw = (const float*)d_in[9];
    const float* pab = (const float*)d_in[10];
    const float* w1  = (const float*)d_in[11];
    const float* bu1 = (const float*)d_in[12];
    const float* ba1 = (const float*)d_in[13];
    const float* w2  = (const float*)d_in[14];
    const float* bu2 = (const float*)d_in[15];
    const float* ba2 = (const float*)d_in[16];
    const float* wcp = (const float*)d_in[17];
    const float* buc = (const float*)d_in[18];
    const float* bac = (const float*)d_in[19];
    float* out = (float*)d_out;

    float* ws    = (float*)d_ws;
    float* y     = ws;               // 64*16*16*64      = 1048576
    float* poseP = y + 1048576;      // 64*16*16*128     = 2097152
    float* aP    = poseP + 2097152;  // 64*16*16*8       = 131072
    float* pose1 = aP + 131072;      // 64*7*7*16*16     = 802816
    float* a1    = pose1 + 802816;   // 64*7*7*16        = 50176
    float* pose2 = a1 + 50176;       // 64*5*5*16*16     = 409600
    float* a2    = pose2 + 409600;   // 64*5*5*16        = 25600
    float* w1t   = a2 + 25600;       // 18432
    float* w2t   = w1t + 18432;      // 36864
    float* wct   = w2t + 36864;      // 2560
    float* wpt   = wct + 2560;       // 65*136 = 8840

    // conv+bn+relu fused with all weight transposes (independent work, one launch)
    const int transw_blocks = (3616 * 16 + 65 * 136 + 255) / 256;   // 261
    hipLaunchKernelGGL(k_conv_transw, dim3(4096 + transw_blocks), dim3(256), 0, stream,
                       x, c1w, c1b, bng, bnb, bnm, bnv, y,
                       w1, w2, wcp, ppw, ppb, paw, pab, w1t, w2t, wct, wpt);
    hipLaunchKernelGGL(k_prim, dim3((16384 * 34 + 255) / 256), dim3(256), 0, stream,
                       y, wpt, poseP, aP);
    // stage 1: N=72, 3136 positions -> 1568 blocks x (NW=2 waves, G=2 positions)
    hipLaunchKernelGGL((k_caps_split2<72, 16, 3, 2, 16, 16, 8, 7, 7, 2>), dim3(1568), dim3(128), 0, stream,
                       poseP, aP, w1t, bu1, ba1, pose1, a1);
    // stage 2: N=144, 1600 positions -> 800 blocks x (NW=2 waves, G=2 positions)
    hipLaunchKernelGGL((k_caps_split2<144, 16, 3, 1, 7, 7, 16, 5, 5, 2>), dim3(800), dim3(128), 0, stream,
                       pose1, a1, w2t, bu2, ba2, pose2, a2);
    // class: N=400, C=10, coords, BLK=1024
    hipLaunchKernelGGL((k_caps_class<400, 10, 5, 5, 16, 1024>), dim3(64), dim3(1024), 0, stream,
                       pose2, a2, wct, buc, bac, out);
}